// Round 7
// baseline (126.785 us; speedup 1.0000x reference)
//
#include <hip/hip_runtime.h>

// Chamfer loss: B=8, P=32, N=M=1024, fp32 in, scalar fp32 out.
// Reference quirk: x[bp,m,c] = rp[bp, (3m+c)%M, (3m+c)>>10]  (torch permute+reshape).
//
// R11: symmetry split. R10 profiling: ~49us/iter is an unavoidable harness
// floor (256MB workspace re-poison fill at ~40.6us + launch overhead); main's
// ~35us was LDS-pipe-bound (per-tile swizzle + ds_atomic_min col merge = 2/3
// of DS traffic). Chamfer is symmetric: col-mins of D = row-mins of D^T. So:
//  - 512 blocks = (bp, dir): dir0 computes D (A=x rows, B=y cols), dir1
//    computes D^T (A=y rows, B=x cols) using the SAME verified 30-slot
//    fp32-emulation patterns with roles swapped. Both keep ONLY register
//    row-mins -> per-tile work is 1 ds_read_b128 + 4 MFMA + 16 v_min. No
//    col-min path, no LDS atomics, no workspace, no second kernel.
//  - MFMA work doubles (idle pipe, ~5us) to delete ~20us of LDS+VALU+launch.
//  - Wave owns 64 rows = 4 stripes of 16 -> one 1KB B-frag read feeds 4
//    MFMAs. LDS 65.6KB -> 2 blocks/CU, 8 waves/SIMD target.
// Row-min reduce: DPP ror(1,2,4,8) within 16-lane groups; group sums merged
// via swizzle xor16 + bpermute xor32; one atomicAdd per block.

#define MM 1024
#define NN 1024
#define THREADS 1024
#define NWAVES 16
#define FINF 3.4e38f

typedef float f32x4 __attribute__((ext_vector_type(4)));
typedef __bf16 bf16x8 __attribute__((ext_vector_type(8)));

#define BT_OFF 0                      // B tiles: 64 x 1KB
#define PAD_OFF 65536                 // 1KB pad (last prefetch lands here)
#define RS_OFF (PAD_OFF + 1024)      // rowsumS[16]
#define LDS_BYTES (RS_OFF + 64)       // 66624 <= 81920 -> 2 blocks/CU

__device__ __forceinline__ unsigned short bf16_rne(float v) {
    unsigned u = __float_as_uint(v);
    u = u + 0x7FFFu + ((u >> 16) & 1u);
    return (unsigned short)(u >> 16);
}
__device__ __forceinline__ float bf16f(unsigned short h) {
    return __uint_as_float(((unsigned)h) << 16);
}
struct S3 { unsigned short h0, h1, h2; };
__device__ __forceinline__ S3 split3(float v) {
    S3 o;
    o.h0 = bf16_rne(v);
    float r = v - bf16f(o.h0);
    o.h1 = bf16_rne(r);
    float r2 = r - bf16f(o.h1);
    o.h2 = bf16_rne(r2);
    return o;
}
__device__ __forceinline__ unsigned pk(unsigned short a, unsigned short b) {
    return (unsigned)a | ((unsigned)b << 16);
}
template <int CTRL>
__device__ __forceinline__ float dpp_ror_min(float v) {
    int vi = __float_as_int(v);
    int t  = __builtin_amdgcn_update_dpp(vi, vi, CTRL, 0xf, 0xf, true);
    return fminf(v, __int_as_float(t));
}

__global__ __launch_bounds__(THREADS, 8)
void chamfer_main(const float* __restrict__ nrf,   // (BP, N, 3) -> y (straight)
                  const float* __restrict__ rp,    // (BP, M, 3) -> x (scrambled)
                  float* __restrict__ out,
                  float inv_bpm, float inv_bpn) {
    __shared__ __align__(16) unsigned char smem[LDS_BYTES];
    float* rowsumS = (float*)(smem + RS_OFF);

    const int bp   = blockIdx.x >> 1;
    const int dir  = blockIdx.x & 1;   // 0: D (x rows, y cols); 1: D^T
    const int tid  = threadIdx.x;
    const int lane = tid & 63;
    const int wave = tid >> 6;
    const int l15  = lane & 15;
    const int g    = lane >> 4;        // k-chunk / row-group id (0..3)
    const unsigned short ONE = 0x3F80;

    const float* yB = nrf + (size_t)bp * NN * 3;
    const float* xB = rp + (size_t)bp * MM * 3;

    // ---- B panel: column c's 32 slots, tile-packed [c>>4][c&15][4 x uint4].
    // dir0: B = y (straight). dir1: B = x (scrambled view).
    {
        const int c = tid;
        float v0, v1, v2;
        if (dir == 0) {
            v0 = yB[c * 3 + 0]; v1 = yB[c * 3 + 1]; v2 = yB[c * 3 + 2];
        } else {
            const int k = 3 * c;
            v0 = xB[((k    ) & (MM - 1)) * 3 + ((k    ) >> 10)];
            v1 = xB[((k + 1) & (MM - 1)) * 3 + ((k + 1) >> 10)];
            v2 = xB[((k + 2) & (MM - 1)) * 3 + ((k + 2) >> 10)];
        }
        float nn = __builtin_fmaf(v0, v0, __builtin_fmaf(v1, v1, v2 * v2));
        S3 b0 = split3(v0), b1 = split3(v1), b2 = split3(v2), q = split3(nn);
        uint4* dst = (uint4*)(smem + BT_OFF + (c >> 4) * 1024 + (c & 15) * 64);
        dst[0] = make_uint4(pk(b0.h0, b0.h1), pk(b0.h0, b0.h1), pk(b0.h2, b0.h0), pk(b1.h0, b1.h1));
        dst[1] = make_uint4(pk(b1.h0, b1.h1), pk(b1.h2, b1.h0), pk(b2.h0, b2.h1), pk(b2.h0, b2.h1));
        dst[2] = make_uint4(pk(b2.h2, b2.h0), pk(ONE, ONE), pk(ONE, q.h0), pk(q.h1, q.h2));
        dst[3] = make_uint4(pk(b0.h2, b0.h1), pk(b1.h2, b1.h1), pk(b2.h2, b2.h1), 0u);
    }

    // ---- A-fragments (4 stripes of 16 rows; wave owns rows wave*64..+63).
    // dir0: A = x (scrambled). dir1: A = y (straight).
    bf16x8 af[4];
    #pragma unroll
    for (int s = 0; s < 4; ++s) {
        const int m = wave * 64 + s * 16 + l15;
        float v0, v1, v2;
        if (dir == 0) {
            const int k = 3 * m;
            v0 = xB[((k    ) & (MM - 1)) * 3 + ((k    ) >> 10)];
            v1 = xB[((k + 1) & (MM - 1)) * 3 + ((k + 1) >> 10)];
            v2 = xB[((k + 2) & (MM - 1)) * 3 + ((k + 2) >> 10)];
        } else {
            v0 = yB[m * 3 + 0]; v1 = yB[m * 3 + 1]; v2 = yB[m * 3 + 2];
        }
        float nn = __builtin_fmaf(v0, v0, __builtin_fmaf(v1, v1, v2 * v2));
        S3 a0 = split3(-2.0f * v0), a1 = split3(-2.0f * v1), a2 = split3(-2.0f * v2);
        S3 p = split3(nn);
        uint4 q0 = make_uint4(pk(a0.h0, a0.h0), pk(a0.h1, a0.h1), pk(a0.h0, a0.h2), pk(a1.h0, a1.h0));
        uint4 q1 = make_uint4(pk(a1.h1, a1.h1), pk(a1.h0, a1.h2), pk(a2.h0, a2.h0), pk(a2.h1, a2.h1));
        uint4 q2 = make_uint4(pk(a2.h0, a2.h2), pk(p.h0, p.h1), pk(p.h2, ONE), pk(ONE, ONE));
        uint4 q3 = make_uint4(pk(a0.h1, a0.h2), pk(a1.h1, a1.h2), pk(a2.h1, a2.h2), 0u);
        uint4 sel = (g == 0) ? q0 : (g == 1) ? q1 : (g == 2) ? q2 : q3;
        union { uint4 u; bf16x8 b; } cv; cv.u = sel;
        af[s] = cv.b;
    }
    __syncthreads();

    // ---- main loop: 64 col-tiles; per tile 1 b128 read + 4 MFMA + 16 v_min.
    const unsigned char* BtBase = smem + BT_OFF + (unsigned)((l15 * 4 + g) * 16);
    const f32x4 Z = {0.0f, 0.0f, 0.0f, 0.0f};

    float rmin[4][4];
    #pragma unroll
    for (int s = 0; s < 4; ++s)
        #pragma unroll
        for (int j = 0; j < 4; ++j) rmin[s][j] = FINF;

    bf16x8 bfc = *(const bf16x8*)(BtBase);
    #pragma unroll
    for (int t = 0; t < 64; ++t) {
        // prefetch next tile (t=63 reads the pad region: in-bounds, unused)
        bf16x8 bfn = *(const bf16x8*)(BtBase + (t + 1) * 1024);

        f32x4 acc0 = __builtin_amdgcn_mfma_f32_16x16x32_bf16(af[0], bfc, Z, 0, 0, 0);
        f32x4 acc1 = __builtin_amdgcn_mfma_f32_16x16x32_bf16(af[1], bfc, Z, 0, 0, 0);
        f32x4 acc2 = __builtin_amdgcn_mfma_f32_16x16x32_bf16(af[2], bfc, Z, 0, 0, 0);
        f32x4 acc3 = __builtin_amdgcn_mfma_f32_16x16x32_bf16(af[3], bfc, Z, 0, 0, 0);

        #pragma unroll
        for (int j = 0; j < 4; ++j) {
            rmin[0][j] = fminf(rmin[0][j], acc0[j]);
            rmin[1][j] = fminf(rmin[1][j], acc1[j]);
            rmin[2][j] = fminf(rmin[2][j], acc2[j]);
            rmin[3][j] = fminf(rmin[3][j], acc3[j]);
        }
        bfc = bfn;
    }

    // ---- row-min: min over cols = over the 16 lanes of each row group.
    float rowsum = 0.0f;
    #pragma unroll
    for (int s = 0; s < 4; ++s) {
        #pragma unroll
        for (int j = 0; j < 4; ++j) {
            float v = rmin[s][j];
            v = dpp_ror_min<0x121>(v);
            v = dpp_ror_min<0x122>(v);
            v = dpp_ror_min<0x124>(v);
            v = dpp_ror_min<0x128>(v);   // min over the 16 lanes of group g
            rowsum += v;                 // row = s*16 + g*4 + j, all distinct
        }
    }
    // sum across the 4 groups: xor16 (swizzle) + xor32 (bpermute)
    rowsum += __int_as_float(__builtin_amdgcn_ds_swizzle(__float_as_int(rowsum), 0x401F));
    rowsum += __int_as_float(__builtin_amdgcn_ds_bpermute((lane ^ 32) << 2, __float_as_int(rowsum)));
    if (lane == 0) rowsumS[wave] = rowsum;
    __syncthreads();

    if (tid < 64) {
        float r = (tid < NWAVES) ? rowsumS[tid] : 0.0f;
        #pragma unroll
        for (int off = 8; off > 0; off >>= 1) r += __shfl_xor(r, off, 64);
        if (tid == 0) atomicAdd(out, r * (dir ? inv_bpn : inv_bpm));
    }
}

extern "C" void kernel_launch(void* const* d_in, const int* in_sizes, int n_in,
                              void* d_out, int out_size, void* d_ws, size_t ws_size,
                              hipStream_t stream) {
    const float* nrf = (const float*)d_in[0];  // (B,P,N,3)
    const float* rp  = (const float*)d_in[1];  // (B,P,M,3)
    float* out = (float*)d_out;

    const int BP = in_sizes[1] / (MM * 3);     // 256
    const float inv_bpm = 1.0f / (float)(BP * MM);
    const float inv_bpn = 1.0f / (float)(BP * NN);

    (void)hipMemsetAsync(out, 0, sizeof(float), stream);
    chamfer_main<<<BP * 2, THREADS, 0, stream>>>(nrf, rp, out, inv_bpm, inv_bpn);
}

// Round 8
// 88.252 us; speedup vs baseline: 1.4366x; 1.4366x over previous
//
#include <hip/hip_runtime.h>

// Chamfer loss: B=8, P=32, N=M=1024, fp32 in, scalar fp32 out.
// Reference quirk: x[bp,m,c] = rp[bp, (3m+c)%M, (3m+c)>>10]  (torch permute+reshape).
//
// R12: R11 (symmetry split: dir0 computes D row-mins, dir1 computes D^T
// row-mins; no col-min path, no LDS atomics, no workspace) with two fixes:
//  1. __launch_bounds__(1024, 4): R11's (,8) capped the unified reg file at
//     64/wave vs ~75 live -> catastrophic scratch spill (WRITE_SIZE=163MB,
//     VGPR_Count=32, main 73us). (,4) caps at 128 -> zero spill, 4 waves/SIMD.
//  2. Quad-rotate LDS swizzle: col c's quad q at (c&15)*64 + ((q+(c>>1))&3)*16
//     (reads: quad g at ((g+(l15>>1))&3)*16). R11's linear layout put b128
//     chunk-starts on 2 banks per 16-lane phase (8-way alias, 2.88M conflicts);
//     rotation spreads starts over 8 slots, <=2 touches/bank -> conflict-free
//     under both quarter-wave and full-wave LDS phasing.
// Main loop per tile: 1 ds_read_b128 (1-ahead prefetch) + 4 MFMA
// (mfma_f32_16x16x32_bf16, one per 16-row stripe) + 16 v_min. Row-min reduce:
// DPP ror(1,2,4,8) in 16-lane groups + swizzle/bpermute sum; 1 atomicAdd/block.

#define MM 1024
#define NN 1024
#define THREADS 1024
#define NWAVES 16
#define FINF 3.4e38f

typedef float f32x4 __attribute__((ext_vector_type(4)));
typedef __bf16 bf16x8 __attribute__((ext_vector_type(8)));

#define BT_OFF 0                      // B tiles: 64 x 1KB
#define PAD_OFF 65536                 // 1KB pad (last prefetch lands here)
#define RS_OFF (PAD_OFF + 1024)       // rowsumS[16]
#define LDS_BYTES (RS_OFF + 64)       // 66624 bytes

__device__ __forceinline__ unsigned short bf16_rne(float v) {
    unsigned u = __float_as_uint(v);
    u = u + 0x7FFFu + ((u >> 16) & 1u);
    return (unsigned short)(u >> 16);
}
__device__ __forceinline__ float bf16f(unsigned short h) {
    return __uint_as_float(((unsigned)h) << 16);
}
struct S3 { unsigned short h0, h1, h2; };
__device__ __forceinline__ S3 split3(float v) {
    S3 o;
    o.h0 = bf16_rne(v);
    float r = v - bf16f(o.h0);
    o.h1 = bf16_rne(r);
    float r2 = r - bf16f(o.h1);
    o.h2 = bf16_rne(r2);
    return o;
}
__device__ __forceinline__ unsigned pk(unsigned short a, unsigned short b) {
    return (unsigned)a | ((unsigned)b << 16);
}
template <int CTRL>
__device__ __forceinline__ float dpp_ror_min(float v) {
    int vi = __float_as_int(v);
    int t  = __builtin_amdgcn_update_dpp(vi, vi, CTRL, 0xf, 0xf, true);
    return fminf(v, __int_as_float(t));
}

__global__ __launch_bounds__(THREADS, 4)
void chamfer_main(const float* __restrict__ nrf,   // (BP, N, 3) -> y (straight)
                  const float* __restrict__ rp,    // (BP, M, 3) -> x (scrambled)
                  float* __restrict__ out,
                  float inv_bpm, float inv_bpn) {
    __shared__ __align__(16) unsigned char smem[LDS_BYTES];
    float* rowsumS = (float*)(smem + RS_OFF);

    const int bp   = blockIdx.x >> 1;
    const int dir  = blockIdx.x & 1;   // 0: D (x rows, y cols); 1: D^T
    const int tid  = threadIdx.x;
    const int lane = tid & 63;
    const int wave = tid >> 6;
    const int l15  = lane & 15;
    const int g    = lane >> 4;        // k-chunk / row-group id (0..3)
    const unsigned short ONE = 0x3F80;

    const float* yB = nrf + (size_t)bp * NN * 3;
    const float* xB = rp + (size_t)bp * MM * 3;

    // ---- B panel: column c's 32 slots, tile-packed with quad-rotate swizzle:
    // quad q of col c at [c>>4]*1024 + (c&15)*64 + ((q + (c>>1))&3)*16.
    {
        const int c = tid;
        float v0, v1, v2;
        if (dir == 0) {
            v0 = yB[c * 3 + 0]; v1 = yB[c * 3 + 1]; v2 = yB[c * 3 + 2];
        } else {
            const int k = 3 * c;
            v0 = xB[((k    ) & (MM - 1)) * 3 + ((k    ) >> 10)];
            v1 = xB[((k + 1) & (MM - 1)) * 3 + ((k + 1) >> 10)];
            v2 = xB[((k + 2) & (MM - 1)) * 3 + ((k + 2) >> 10)];
        }
        float nn = __builtin_fmaf(v0, v0, __builtin_fmaf(v1, v1, v2 * v2));
        S3 b0 = split3(v0), b1 = split3(v1), b2 = split3(v2), q = split3(nn);
        uint4 qd[4];
        qd[0] = make_uint4(pk(b0.h0, b0.h1), pk(b0.h0, b0.h1), pk(b0.h2, b0.h0), pk(b1.h0, b1.h1));
        qd[1] = make_uint4(pk(b1.h0, b1.h1), pk(b1.h2, b1.h0), pk(b2.h0, b2.h1), pk(b2.h0, b2.h1));
        qd[2] = make_uint4(pk(b2.h2, b2.h0), pk(ONE, ONE), pk(ONE, q.h0), pk(q.h1, q.h2));
        qd[3] = make_uint4(pk(b0.h2, b0.h1), pk(b1.h2, b1.h1), pk(b2.h2, b2.h1), 0u);
        unsigned char* colBase = smem + BT_OFF + (c >> 4) * 1024 + (c & 15) * 64;
        const int rot = (c >> 1) & 3;
        #pragma unroll
        for (int qq = 0; qq < 4; ++qq)
            *(uint4*)(colBase + (((qq + rot) & 3) * 16)) = qd[qq];
    }

    // ---- A-fragments (4 stripes of 16 rows; wave owns rows wave*64..+63).
    bf16x8 af[4];
    #pragma unroll
    for (int s = 0; s < 4; ++s) {
        const int m = wave * 64 + s * 16 + l15;
        float v0, v1, v2;
        if (dir == 0) {
            const int k = 3 * m;
            v0 = xB[((k    ) & (MM - 1)) * 3 + ((k    ) >> 10)];
            v1 = xB[((k + 1) & (MM - 1)) * 3 + ((k + 1) >> 10)];
            v2 = xB[((k + 2) & (MM - 1)) * 3 + ((k + 2) >> 10)];
        } else {
            v0 = yB[m * 3 + 0]; v1 = yB[m * 3 + 1]; v2 = yB[m * 3 + 2];
        }
        float nn = __builtin_fmaf(v0, v0, __builtin_fmaf(v1, v1, v2 * v2));
        S3 a0 = split3(-2.0f * v0), a1 = split3(-2.0f * v1), a2 = split3(-2.0f * v2);
        S3 p = split3(nn);
        uint4 q0 = make_uint4(pk(a0.h0, a0.h0), pk(a0.h1, a0.h1), pk(a0.h0, a0.h2), pk(a1.h0, a1.h0));
        uint4 q1 = make_uint4(pk(a1.h1, a1.h1), pk(a1.h0, a1.h2), pk(a2.h0, a2.h0), pk(a2.h1, a2.h1));
        uint4 q2 = make_uint4(pk(a2.h0, a2.h2), pk(p.h0, p.h1), pk(p.h2, ONE), pk(ONE, ONE));
        uint4 q3 = make_uint4(pk(a0.h1, a0.h2), pk(a1.h1, a1.h2), pk(a2.h1, a2.h2), 0u);
        uint4 sel = (g == 0) ? q0 : (g == 1) ? q1 : (g == 2) ? q2 : q3;
        union { uint4 u; bf16x8 b; } cv; cv.u = sel;
        af[s] = cv.b;
    }
    __syncthreads();

    // ---- main loop: 64 col-tiles; per tile 1 b128 read + 4 MFMA + 16 v_min.
    // Lane (l15, g) reads col l15's quad g at swizzled offset.
    const unsigned char* BtBase = smem + BT_OFF + (unsigned)(l15 * 64)
                                + (unsigned)((((g + (l15 >> 1)) & 3) * 16));
    const f32x4 Z = {0.0f, 0.0f, 0.0f, 0.0f};

    float rmin[4][4];
    #pragma unroll
    for (int s = 0; s < 4; ++s)
        #pragma unroll
        for (int j = 0; j < 4; ++j) rmin[s][j] = FINF;

    bf16x8 bfc = *(const bf16x8*)(BtBase);
    #pragma unroll
    for (int t = 0; t < 64; ++t) {
        // prefetch next tile (t=63 reads the pad region: in-bounds, unused)
        bf16x8 bfn = *(const bf16x8*)(BtBase + (t + 1) * 1024);

        f32x4 acc0 = __builtin_amdgcn_mfma_f32_16x16x32_bf16(af[0], bfc, Z, 0, 0, 0);
        f32x4 acc1 = __builtin_amdgcn_mfma_f32_16x16x32_bf16(af[1], bfc, Z, 0, 0, 0);
        f32x4 acc2 = __builtin_amdgcn_mfma_f32_16x16x32_bf16(af[2], bfc, Z, 0, 0, 0);
        f32x4 acc3 = __builtin_amdgcn_mfma_f32_16x16x32_bf16(af[3], bfc, Z, 0, 0, 0);

        #pragma unroll
        for (int j = 0; j < 4; ++j) {
            rmin[0][j] = fminf(rmin[0][j], acc0[j]);
            rmin[1][j] = fminf(rmin[1][j], acc1[j]);
            rmin[2][j] = fminf(rmin[2][j], acc2[j]);
            rmin[3][j] = fminf(rmin[3][j], acc3[j]);
        }
        bfc = bfn;
    }

    // ---- row-min: min over cols = over the 16 lanes of each row group.
    float rowsum = 0.0f;
    #pragma unroll
    for (int s = 0; s < 4; ++s) {
        #pragma unroll
        for (int j = 0; j < 4; ++j) {
            float v = rmin[s][j];
            v = dpp_ror_min<0x121>(v);
            v = dpp_ror_min<0x122>(v);
            v = dpp_ror_min<0x124>(v);
            v = dpp_ror_min<0x128>(v);   // min over the 16 lanes of group g
            rowsum += v;                 // row = s*16 + g*4 + j, all distinct
        }
    }
    // sum across the 4 groups: xor16 (swizzle) + xor32 (bpermute)
    rowsum += __int_as_float(__builtin_amdgcn_ds_swizzle(__float_as_int(rowsum), 0x401F));
    rowsum += __int_as_float(__builtin_amdgcn_ds_bpermute((lane ^ 32) << 2, __float_as_int(rowsum)));
    if (lane == 0) rowsumS[wave] = rowsum;
    __syncthreads();

    if (tid < 64) {
        float r = (tid < NWAVES) ? rowsumS[tid] : 0.0f;
        #pragma unroll
        for (int off = 8; off > 0; off >>= 1) r += __shfl_xor(r, off, 64);
        if (tid == 0) atomicAdd(out, r * (dir ? inv_bpn : inv_bpm));
    }
}

extern "C" void kernel_launch(void* const* d_in, const int* in_sizes, int n_in,
                              void* d_out, int out_size, void* d_ws, size_t ws_size,
                              hipStream_t stream) {
    const float* nrf = (const float*)d_in[0];  // (B,P,N,3)
    const float* rp  = (const float*)d_in[1];  // (B,P,M,3)
    float* out = (float*)d_out;

    const int BP = in_sizes[1] / (MM * 3);     // 256
    const float inv_bpm = 1.0f / (float)(BP * MM);
    const float inv_bpn = 1.0f / (float)(BP * NN);

    (void)hipMemsetAsync(out, 0, sizeof(float), stream);
    chamfer_main<<<BP * 2, THREADS, 0, stream>>>(nrf, rp, out, inv_bpm, inv_bpn);
}

// Round 9
// 86.896 us; speedup vs baseline: 1.4590x; 1.0156x over previous
//
#include <hip/hip_runtime.h>

// Chamfer loss: B=8, P=32, N=M=1024, fp32 in, scalar fp32 out.
// Reference quirk: x[bp,m,c] = rp[bp, (3m+c)%M, (3m+c)>>10]  (torch permute+reshape).
//
// R13: R12 with the main loop re-pipelined for bounded register pressure.
// Diagnosis: R12 main ~= 38.6us (dur - 40.6 fill - 9 OH) vs ~8us issue-rate
// model. R11 proved unroll-64 + reg cap -> catastrophic spill; R12 kept the
// FULL 64-iter unroll (scheduler hoists dozens of prefetches/accs past the
// 128 cap -> suspected moderate spill, invisible because main's counters are
// masked by the 40.3us harness fills). Fixes:
//  1. 2-tile software pipeline with #pragma unroll 2: <=4 tiles in flight,
//     ~70 live regs by construction -> spill impossible under the 128 cap.
//  2. min3 merge: rmin = v_min3(rmin, accA, accB) per 2 tiles -> 16 min3
//     instead of 32 v_min (halves the dominant VALU term; exact, min is
//     order-insensitive here).
// Everything else byte-identical to R12: symmetry split (dir0: D row-mins,
// dir1: D^T row-mins), 30-slot split-3 fp32 emulation (absmax 0.0 across
// R5-R12), quad-rotate conflict-free LDS layout, DPP/swizzle reduce,
// 1 atomicAdd per block.

#define MM 1024
#define NN 1024
#define THREADS 1024
#define NWAVES 16
#define FINF 3.4e38f

typedef float f32x4 __attribute__((ext_vector_type(4)));
typedef __bf16 bf16x8 __attribute__((ext_vector_type(8)));

#define BT_OFF 0                      // B tiles: 64 x 1KB
#define PAD_OFF 65536                 // 2KB pad (2-deep prefetch lands here)
#define RS_OFF (PAD_OFF + 2048)       // rowsumS[16]
#define LDS_BYTES (RS_OFF + 64)       // 67648 bytes -> 2 blocks/CU by LDS

__device__ __forceinline__ unsigned short bf16_rne(float v) {
    unsigned u = __float_as_uint(v);
    u = u + 0x7FFFu + ((u >> 16) & 1u);
    return (unsigned short)(u >> 16);
}
__device__ __forceinline__ float bf16f(unsigned short h) {
    return __uint_as_float(((unsigned)h) << 16);
}
struct S3 { unsigned short h0, h1, h2; };
__device__ __forceinline__ S3 split3(float v) {
    S3 o;
    o.h0 = bf16_rne(v);
    float r = v - bf16f(o.h0);
    o.h1 = bf16_rne(r);
    float r2 = r - bf16f(o.h1);
    o.h2 = bf16_rne(r2);
    return o;
}
__device__ __forceinline__ unsigned pk(unsigned short a, unsigned short b) {
    return (unsigned)a | ((unsigned)b << 16);
}
__device__ __forceinline__ float min3f(float a, float b, float c) {
    return fminf(fminf(a, b), c);   // folds to v_min3_f32
}
template <int CTRL>
__device__ __forceinline__ float dpp_ror_min(float v) {
    int vi = __float_as_int(v);
    int t  = __builtin_amdgcn_update_dpp(vi, vi, CTRL, 0xf, 0xf, true);
    return fminf(v, __int_as_float(t));
}

__global__ __launch_bounds__(THREADS, 4)
void chamfer_main(const float* __restrict__ nrf,   // (BP, N, 3) -> y (straight)
                  const float* __restrict__ rp,    // (BP, M, 3) -> x (scrambled)
                  float* __restrict__ out,
                  float inv_bpm, float inv_bpn) {
    __shared__ __align__(16) unsigned char smem[LDS_BYTES];
    float* rowsumS = (float*)(smem + RS_OFF);

    const int bp   = blockIdx.x >> 1;
    const int dir  = blockIdx.x & 1;   // 0: D (x rows, y cols); 1: D^T
    const int tid  = threadIdx.x;
    const int lane = tid & 63;
    const int wave = tid >> 6;
    const int l15  = lane & 15;
    const int g    = lane >> 4;        // k-chunk / row-group id (0..3)
    const unsigned short ONE = 0x3F80;

    const float* yB = nrf + (size_t)bp * NN * 3;
    const float* xB = rp + (size_t)bp * MM * 3;

    // ---- B panel: column c's 32 slots, tile-packed with quad-rotate swizzle:
    // quad q of col c at [c>>4]*1024 + (c&15)*64 + ((q + (c>>1))&3)*16.
    {
        const int c = tid;
        float v0, v1, v2;
        if (dir == 0) {
            v0 = yB[c * 3 + 0]; v1 = yB[c * 3 + 1]; v2 = yB[c * 3 + 2];
        } else {
            const int k = 3 * c;
            v0 = xB[((k    ) & (MM - 1)) * 3 + ((k    ) >> 10)];
            v1 = xB[((k + 1) & (MM - 1)) * 3 + ((k + 1) >> 10)];
            v2 = xB[((k + 2) & (MM - 1)) * 3 + ((k + 2) >> 10)];
        }
        float nn = __builtin_fmaf(v0, v0, __builtin_fmaf(v1, v1, v2 * v2));
        S3 b0 = split3(v0), b1 = split3(v1), b2 = split3(v2), q = split3(nn);
        uint4 qd[4];
        qd[0] = make_uint4(pk(b0.h0, b0.h1), pk(b0.h0, b0.h1), pk(b0.h2, b0.h0), pk(b1.h0, b1.h1));
        qd[1] = make_uint4(pk(b1.h0, b1.h1), pk(b1.h2, b1.h0), pk(b2.h0, b2.h1), pk(b2.h0, b2.h1));
        qd[2] = make_uint4(pk(b2.h2, b2.h0), pk(ONE, ONE), pk(ONE, q.h0), pk(q.h1, q.h2));
        qd[3] = make_uint4(pk(b0.h2, b0.h1), pk(b1.h2, b1.h1), pk(b2.h2, b2.h1), 0u);
        unsigned char* colBase = smem + BT_OFF + (c >> 4) * 1024 + (c & 15) * 64;
        const int rot = (c >> 1) & 3;
        #pragma unroll
        for (int qq = 0; qq < 4; ++qq)
            *(uint4*)(colBase + (((qq + rot) & 3) * 16)) = qd[qq];
    }

    // ---- A-fragments (4 stripes of 16 rows; wave owns rows wave*64..+63).
    bf16x8 af[4];
    #pragma unroll
    for (int s = 0; s < 4; ++s) {
        const int m = wave * 64 + s * 16 + l15;
        float v0, v1, v2;
        if (dir == 0) {
            const int k = 3 * m;
            v0 = xB[((k    ) & (MM - 1)) * 3 + ((k    ) >> 10)];
            v1 = xB[((k + 1) & (MM - 1)) * 3 + ((k + 1) >> 10)];
            v2 = xB[((k + 2) & (MM - 1)) * 3 + ((k + 2) >> 10)];
        } else {
            v0 = yB[m * 3 + 0]; v1 = yB[m * 3 + 1]; v2 = yB[m * 3 + 2];
        }
        float nn = __builtin_fmaf(v0, v0, __builtin_fmaf(v1, v1, v2 * v2));
        S3 a0 = split3(-2.0f * v0), a1 = split3(-2.0f * v1), a2 = split3(-2.0f * v2);
        S3 p = split3(nn);
        uint4 q0 = make_uint4(pk(a0.h0, a0.h0), pk(a0.h1, a0.h1), pk(a0.h0, a0.h2), pk(a1.h0, a1.h0));
        uint4 q1 = make_uint4(pk(a1.h1, a1.h1), pk(a1.h0, a1.h2), pk(a2.h0, a2.h0), pk(a2.h1, a2.h1));
        uint4 q2 = make_uint4(pk(a2.h0, a2.h2), pk(p.h0, p.h1), pk(p.h2, ONE), pk(ONE, ONE));
        uint4 q3 = make_uint4(pk(a0.h1, a0.h2), pk(a1.h1, a1.h2), pk(a2.h1, a2.h2), 0u);
        uint4 sel = (g == 0) ? q0 : (g == 1) ? q1 : (g == 2) ? q2 : q3;
        union { uint4 u; bf16x8 b; } cv; cv.u = sel;
        af[s] = cv.b;
    }
    __syncthreads();

    // ---- main loop: 2-tile software pipeline, bounded unroll.
    // Lane (l15, g) reads col l15's quad g at swizzled offset (conflict-free).
    const unsigned char* BtBase = smem + BT_OFF + (unsigned)(l15 * 64)
                                + (unsigned)((((g + (l15 >> 1)) & 3) * 16));
    const f32x4 Z = {0.0f, 0.0f, 0.0f, 0.0f};

    float rmin[4][4];
    #pragma unroll
    for (int s = 0; s < 4; ++s)
        #pragma unroll
        for (int j = 0; j < 4; ++j) rmin[s][j] = FINF;

    bf16x8 c0 = *(const bf16x8*)(BtBase);
    bf16x8 c1 = *(const bf16x8*)(BtBase + 1024);
    #pragma unroll 2
    for (int t = 0; t < 64; t += 2) {
        // prefetch tiles t+2, t+3 (last iter reads the 2KB pad: unused)
        bf16x8 n0 = *(const bf16x8*)(BtBase + (t + 2) * 1024);
        bf16x8 n1 = *(const bf16x8*)(BtBase + (t + 3) * 1024);

        #pragma unroll
        for (int s = 0; s < 4; ++s) {
            f32x4 aA = __builtin_amdgcn_mfma_f32_16x16x32_bf16(af[s], c0, Z, 0, 0, 0);
            f32x4 aB = __builtin_amdgcn_mfma_f32_16x16x32_bf16(af[s], c1, Z, 0, 0, 0);
            #pragma unroll
            for (int j = 0; j < 4; ++j)
                rmin[s][j] = min3f(rmin[s][j], aA[j], aB[j]);
        }
        c0 = n0; c1 = n1;
    }

    // ---- row-min: min over cols = over the 16 lanes of each row group.
    float rowsum = 0.0f;
    #pragma unroll
    for (int s = 0; s < 4; ++s) {
        #pragma unroll
        for (int j = 0; j < 4; ++j) {
            float v = rmin[s][j];
            v = dpp_ror_min<0x121>(v);
            v = dpp_ror_min<0x122>(v);
            v = dpp_ror_min<0x124>(v);
            v = dpp_ror_min<0x128>(v);   // min over the 16 lanes of group g
            rowsum += v;                 // row = s*16 + g*4 + j, all distinct
        }
    }
    // sum across the 4 groups: xor16 (swizzle) + xor32 (bpermute)
    rowsum += __int_as_float(__builtin_amdgcn_ds_swizzle(__float_as_int(rowsum), 0x401F));
    rowsum += __int_as_float(__builtin_amdgcn_ds_bpermute((lane ^ 32) << 2, __float_as_int(rowsum)));
    if (lane == 0) rowsumS[wave] = rowsum;
    __syncthreads();

    if (tid < 64) {
        float r = (tid < NWAVES) ? rowsumS[tid] : 0.0f;
        #pragma unroll
        for (int off = 8; off > 0; off >>= 1) r += __shfl_xor(r, off, 64);
        if (tid == 0) atomicAdd(out, r * (dir ? inv_bpn : inv_bpm));
    }
}

extern "C" void kernel_launch(void* const* d_in, const int* in_sizes, int n_in,
                              void* d_out, int out_size, void* d_ws, size_t ws_size,
                              hipStream_t stream) {
    const float* nrf = (const float*)d_in[0];  // (B,P,N,3)
    const float* rp  = (const float*)d_in[1];  // (B,P,M,3)
    float* out = (float*)d_out;

    const int BP = in_sizes[1] / (MM * 3);     // 256
    const float inv_bpm = 1.0f / (float)(BP * MM);
    const float inv_bpn = 1.0f / (float)(BP * NN);

    (void)hipMemsetAsync(out, 0, sizeof(float), stream);
    chamfer_main<<<BP * 2, THREADS, 0, stream>>>(nrf, rp, out, inv_bpm, inv_bpn);
}

// Round 10
// 86.739 us; speedup vs baseline: 1.4617x; 1.0018x over previous
//
#include <hip/hip_runtime.h>

// Chamfer loss: B=8, P=32, N=M=1024, fp32 in, scalar fp32 out.
// Reference quirk: x[bp,m,c] = rp[bp, (3m+c)%M, (3m+c)>>10]  (torch permute+reshape).
//
// R14: halve MFMA volume. Overhead model (solid across R0-R13): dur = 40.6us
// harness fill + ~8.5us launch + kernels. R10/R12/R13 all plateau main~36-39us;
// the invariant is MFMA work: R13's symmetry split = 34.4 GFLOP = ~17us at the
// 2075TF ubench ceiling, ~30us at the harness's ~1.3-1.5GHz effective clock ->
// R13 was ~80% of the throttled MFMA roofline. So:
//  - 256 blocks (1 bp each = 1 block/CU), each computes D ONCE: row-mins in
//    registers (min_x_to_y) AND col-mins of the same tiles (min_y_to_x).
//  - col-min without atomics (R10's mistake): per tile, min3 tree (10 ops) +
//    swizzle xor16 + bpermute xor32 -> full 64-row col-min in every lane;
//    lanes 0-15 ds_write_b32 to per-wave colW[16][1024] (conflict-free);
//    epilogue merges 16 waves in-block. No workspace, no 2nd kernel.
// Per 2-tile iter: 2 ds_read_b128 + 8 MFMA + 16 min3 (rmin) + 2x(10 min tree
// + swizzle + bpermute + masked store). MFMA/SIMD ~20K cyc, VALU ~14K, LDS
// ~23K CU-cyc -> overlapped main ~14-20us.
// Numerics: same 30-slot split-3 fp32 emulation (absmax 0.0 since R5).

#define MM 1024
#define NN 1024
#define THREADS 1024
#define NWAVES 16
#define FINF 3.4e38f

typedef float f32x4 __attribute__((ext_vector_type(4)));
typedef __bf16 bf16x8 __attribute__((ext_vector_type(8)));

#define BT_OFF 0                      // B tiles: 64 x 1KB
#define PAD_OFF 65536                 // 2KB pad (2-deep prefetch lands here)
#define CW_OFF (PAD_OFF + 2048)       // colW[16][1024] f32 = 64KB
#define RS_OFF (CW_OFF + 65536)       // rowsumS[16]
#define CS_OFF (RS_OFF + 64)          // csumS[16]
#define LDS_BYTES (CS_OFF + 64)       // 133248 bytes (1 block/CU; grid=256=CUs)

__device__ __forceinline__ unsigned short bf16_rne(float v) {
    unsigned u = __float_as_uint(v);
    u = u + 0x7FFFu + ((u >> 16) & 1u);
    return (unsigned short)(u >> 16);
}
__device__ __forceinline__ float bf16f(unsigned short h) {
    return __uint_as_float(((unsigned)h) << 16);
}
struct S3 { unsigned short h0, h1, h2; };
__device__ __forceinline__ S3 split3(float v) {
    S3 o;
    o.h0 = bf16_rne(v);
    float r = v - bf16f(o.h0);
    o.h1 = bf16_rne(r);
    float r2 = r - bf16f(o.h1);
    o.h2 = bf16_rne(r2);
    return o;
}
__device__ __forceinline__ unsigned pk(unsigned short a, unsigned short b) {
    return (unsigned)a | ((unsigned)b << 16);
}
__device__ __forceinline__ float min3f(float a, float b, float c) {
    return fminf(fminf(a, b), c);   // folds to v_min3_f32
}
template <int CTRL>
__device__ __forceinline__ float dpp_ror_min(float v) {
    int vi = __float_as_int(v);
    int t  = __builtin_amdgcn_update_dpp(vi, vi, CTRL, 0xf, 0xf, true);
    return fminf(v, __int_as_float(t));
}
// min over a 16x16x32 C-fragment's 4 regs x 4 stripes -> scalar
__device__ __forceinline__ float tile_cmin(const f32x4* a) {
    float u0 = fminf(min3f(a[0][0], a[0][1], a[0][2]), a[0][3]);
    float u1 = fminf(min3f(a[1][0], a[1][1], a[1][2]), a[1][3]);
    float u2 = fminf(min3f(a[2][0], a[2][1], a[2][2]), a[2][3]);
    float u3 = fminf(min3f(a[3][0], a[3][1], a[3][2]), a[3][3]);
    return fminf(fminf(u0, u1), fminf(u2, u3));
}

__global__ __launch_bounds__(THREADS, 4)
void chamfer_main(const float* __restrict__ nrf,   // (BP, N, 3) -> y (straight)
                  const float* __restrict__ rp,    // (BP, M, 3) -> x (scrambled)
                  float* __restrict__ out,
                  float inv_bpm, float inv_bpn) {
    __shared__ __align__(16) unsigned char smem[LDS_BYTES];
    float* colW    = (float*)(smem + CW_OFF);
    float* rowsumS = (float*)(smem + RS_OFF);
    float* csumS   = (float*)(smem + CS_OFF);

    const int bp   = blockIdx.x;
    const int tid  = threadIdx.x;
    const int lane = tid & 63;
    const int wave = tid >> 6;
    const int l15  = lane & 15;
    const int g    = lane >> 4;        // k-chunk / row-group id (0..3)
    const unsigned short ONE = 0x3F80;

    const float* yB = nrf + (size_t)bp * NN * 3;
    const float* xB = rp + (size_t)bp * MM * 3;

    // ---- B panel (y cols): 32 slots, tile-packed with quad-rotate swizzle:
    // quad q of col c at [c>>4]*1024 + (c&15)*64 + ((q + (c>>1))&3)*16.
    {
        const int c = tid;
        float v0 = yB[c * 3 + 0], v1 = yB[c * 3 + 1], v2 = yB[c * 3 + 2];
        float nn = __builtin_fmaf(v0, v0, __builtin_fmaf(v1, v1, v2 * v2));
        S3 b0 = split3(v0), b1 = split3(v1), b2 = split3(v2), q = split3(nn);
        uint4 qd[4];
        qd[0] = make_uint4(pk(b0.h0, b0.h1), pk(b0.h0, b0.h1), pk(b0.h2, b0.h0), pk(b1.h0, b1.h1));
        qd[1] = make_uint4(pk(b1.h0, b1.h1), pk(b1.h2, b1.h0), pk(b2.h0, b2.h1), pk(b2.h0, b2.h1));
        qd[2] = make_uint4(pk(b2.h2, b2.h0), pk(ONE, ONE), pk(ONE, q.h0), pk(q.h1, q.h2));
        qd[3] = make_uint4(pk(b0.h2, b0.h1), pk(b1.h2, b1.h1), pk(b2.h2, b2.h1), 0u);
        unsigned char* colBase = smem + BT_OFF + (c >> 4) * 1024 + (c & 15) * 64;
        const int rot = (c >> 1) & 3;
        #pragma unroll
        for (int qq = 0; qq < 4; ++qq)
            *(uint4*)(colBase + (((qq + rot) & 3) * 16)) = qd[qq];
    }

    // ---- A-fragments (x rows, scrambled view): 4 stripes of 16 rows.
    bf16x8 af[4];
    #pragma unroll
    for (int s = 0; s < 4; ++s) {
        const int m = wave * 64 + s * 16 + l15;
        const int k = 3 * m;
        float v0 = xB[((k    ) & (MM - 1)) * 3 + ((k    ) >> 10)];
        float v1 = xB[((k + 1) & (MM - 1)) * 3 + ((k + 1) >> 10)];
        float v2 = xB[((k + 2) & (MM - 1)) * 3 + ((k + 2) >> 10)];
        float nn = __builtin_fmaf(v0, v0, __builtin_fmaf(v1, v1, v2 * v2));
        S3 a0 = split3(-2.0f * v0), a1 = split3(-2.0f * v1), a2 = split3(-2.0f * v2);
        S3 p = split3(nn);
        uint4 q0 = make_uint4(pk(a0.h0, a0.h0), pk(a0.h1, a0.h1), pk(a0.h0, a0.h2), pk(a1.h0, a1.h0));
        uint4 q1 = make_uint4(pk(a1.h1, a1.h1), pk(a1.h0, a1.h2), pk(a2.h0, a2.h0), pk(a2.h1, a2.h1));
        uint4 q2 = make_uint4(pk(a2.h0, a2.h2), pk(p.h0, p.h1), pk(p.h2, ONE), pk(ONE, ONE));
        uint4 q3 = make_uint4(pk(a0.h1, a0.h2), pk(a1.h1, a1.h2), pk(a2.h1, a2.h2), 0u);
        uint4 sel = (g == 0) ? q0 : (g == 1) ? q1 : (g == 2) ? q2 : q3;
        union { uint4 u; bf16x8 b; } cv; cv.u = sel;
        af[s] = cv.b;
    }
    __syncthreads();

    // ---- main loop: 2-tile pipeline, bounded unroll; row-min AND col-min.
    const unsigned char* BtBase = smem + BT_OFF + (unsigned)(l15 * 64)
                                + (unsigned)((((g + (l15 >> 1)) & 3) * 16));
    const f32x4 Z = {0.0f, 0.0f, 0.0f, 0.0f};
    const int xaddr32 = (lane ^ 32) << 2;
    float* colWrow = colW + wave * 1024 + l15;

    float rmin[4][4];
    #pragma unroll
    for (int s = 0; s < 4; ++s)
        #pragma unroll
        for (int j = 0; j < 4; ++j) rmin[s][j] = FINF;

    bf16x8 c0 = *(const bf16x8*)(BtBase);
    bf16x8 c1 = *(const bf16x8*)(BtBase + 1024);
    #pragma unroll 2
    for (int t = 0; t < 64; t += 2) {
        // prefetch tiles t+2, t+3 (last iter reads the 2KB pad: unused)
        bf16x8 n0 = *(const bf16x8*)(BtBase + (t + 2) * 1024);
        bf16x8 n1 = *(const bf16x8*)(BtBase + (t + 3) * 1024);

        f32x4 aA[4], aB[4];
        #pragma unroll
        for (int s = 0; s < 4; ++s) {
            aA[s] = __builtin_amdgcn_mfma_f32_16x16x32_bf16(af[s], c0, Z, 0, 0, 0);
            aB[s] = __builtin_amdgcn_mfma_f32_16x16x32_bf16(af[s], c1, Z, 0, 0, 0);
        }
        #pragma unroll
        for (int s = 0; s < 4; ++s)
            #pragma unroll
            for (int j = 0; j < 4; ++j)
                rmin[s][j] = min3f(rmin[s][j], aA[s][j], aB[s][j]);

        // per-tile col-min: lane tree -> merge g^1 (swizzle xor16) ->
        // merge g^2 (bpermute xor32) -> lanes 0..15 store.
        {
            float cm = tile_cmin(aA);
            int sw = __builtin_amdgcn_ds_swizzle(__float_as_int(cm), 0x401F);
            cm = fminf(cm, __int_as_float(sw));
            int pz = __builtin_amdgcn_ds_bpermute(xaddr32, __float_as_int(cm));
            cm = fminf(cm, __int_as_float(pz));
            if (g == 0) colWrow[t * 16] = cm;
        }
        {
            float cm = tile_cmin(aB);
            int sw = __builtin_amdgcn_ds_swizzle(__float_as_int(cm), 0x401F);
            cm = fminf(cm, __int_as_float(sw));
            int pz = __builtin_amdgcn_ds_bpermute(xaddr32, __float_as_int(cm));
            cm = fminf(cm, __int_as_float(pz));
            if (g == 0) colWrow[(t + 1) * 16] = cm;
        }
        c0 = n0; c1 = n1;
    }

    // ---- row-min: min over cols = over the 16 lanes of each row group.
    float rowsum = 0.0f;
    #pragma unroll
    for (int s = 0; s < 4; ++s) {
        #pragma unroll
        for (int j = 0; j < 4; ++j) {
            float v = rmin[s][j];
            v = dpp_ror_min<0x121>(v);
            v = dpp_ror_min<0x122>(v);
            v = dpp_ror_min<0x124>(v);
            v = dpp_ror_min<0x128>(v);   // min over the 16 lanes of group g
            rowsum += v;                 // row = s*16 + g*4 + j, all distinct
        }
    }
    // sum across the 4 groups: xor16 (swizzle) + xor32 (bpermute)
    rowsum += __int_as_float(__builtin_amdgcn_ds_swizzle(__float_as_int(rowsum), 0x401F));
    rowsum += __int_as_float(__builtin_amdgcn_ds_bpermute(xaddr32, __float_as_int(rowsum)));
    if (lane == 0) rowsumS[wave] = rowsum;
    __syncthreads();

    // ---- cross-wave col-min merge + column sum (1 col per thread)
    {
        const int c = tid;
        float v = colW[c];
        #pragma unroll
        for (int w = 1; w < NWAVES; ++w) v = fminf(v, colW[w * 1024 + c]);
        float csum = v;
        #pragma unroll
        for (int off = 32; off > 0; off >>= 1) csum += __shfl_xor(csum, off, 64);
        if (lane == 0) csumS[wave] = csum;
    }
    __syncthreads();

    if (tid == 0) {
        float rs = 0.0f, cs = 0.0f;
        #pragma unroll
        for (int w = 0; w < NWAVES; ++w) { rs += rowsumS[w]; cs += csumS[w]; }
        atomicAdd(out, rs * inv_bpm + cs * inv_bpn);
    }
}

extern "C" void kernel_launch(void* const* d_in, const int* in_sizes, int n_in,
                              void* d_out, int out_size, void* d_ws, size_t ws_size,
                              hipStream_t stream) {
    const float* nrf = (const float*)d_in[0];  // (B,P,N,3)
    const float* rp  = (const float*)d_in[1];  // (B,P,M,3)
    float* out = (float*)d_out;

    const int BP = in_sizes[1] / (MM * 3);     // 256
    const float inv_bpm = 1.0f / (float)(BP * MM);
    const float inv_bpn = 1.0f / (float)(BP * NN);

    (void)hipMemsetAsync(out, 0, sizeof(float), stream);
    chamfer_main<<<BP, THREADS, 0, stream>>>(nrf, rp, out, inv_bpm, inv_bpn);
}

// Round 11
// 85.740 us; speedup vs baseline: 1.4787x; 1.0117x over previous
//
#include <hip/hip_runtime.h>

// Chamfer loss: B=8, P=32, N=M=1024, fp32 in, scalar fp32 out.
// Reference quirk: x[bp,m,c] = rp[bp, (3m+c)%M, (3m+c)>>10]  (torch permute+reshape).
//
// R15: R14 with ONE change — A-fragments staged through LDS instead of
// per-lane VALU construction. Evidence: R13/R14 A/B shows main (~36-38us) is
// insensitive to +-2x work on any single pipe (halving MFMA: -0.16us; halving
// min-VALU: -1.3us); the remaining actionable invariant is the common staging
// prologue (~450 VALU/thread). New prologue: each thread builds ONE row's
// 32-slot pattern (~90 VALU) into the B-tile region (quad-rotated), barrier,
// lanes ds_read_b128 their 4 fragments (conflict-free, bit-identical values),
// barrier, B staging overwrites the region as before (~90 VALU). ~450 -> ~180
// VALU/thread. Loop / col-min / reductions byte-identical to R14.
// If this is null too, main is at an environmental floor (DVFS after the
// mandatory 40.6us 256MB re-poison fill + launch overhead) -> roofline.

#define MM 1024
#define NN 1024
#define THREADS 1024
#define NWAVES 16
#define FINF 3.4e38f

typedef float f32x4 __attribute__((ext_vector_type(4)));
typedef __bf16 bf16x8 __attribute__((ext_vector_type(8)));

#define BT_OFF 0                      // B tiles: 64 x 1KB (A panel pre-stage too)
#define PAD_OFF 65536                 // 2KB pad (2-deep prefetch lands here)
#define CW_OFF (PAD_OFF + 2048)       // colW[16][1024] f32 = 64KB
#define RS_OFF (CW_OFF + 65536)       // rowsumS[16]
#define CS_OFF (RS_OFF + 64)          // csumS[16]
#define LDS_BYTES (CS_OFF + 64)       // 133248 bytes (1 block/CU; grid=256=CUs)

__device__ __forceinline__ unsigned short bf16_rne(float v) {
    unsigned u = __float_as_uint(v);
    u = u + 0x7FFFu + ((u >> 16) & 1u);
    return (unsigned short)(u >> 16);
}
__device__ __forceinline__ float bf16f(unsigned short h) {
    return __uint_as_float(((unsigned)h) << 16);
}
struct S3 { unsigned short h0, h1, h2; };
__device__ __forceinline__ S3 split3(float v) {
    S3 o;
    o.h0 = bf16_rne(v);
    float r = v - bf16f(o.h0);
    o.h1 = bf16_rne(r);
    float r2 = r - bf16f(o.h1);
    o.h2 = bf16_rne(r2);
    return o;
}
__device__ __forceinline__ unsigned pk(unsigned short a, unsigned short b) {
    return (unsigned)a | ((unsigned)b << 16);
}
__device__ __forceinline__ float min3f(float a, float b, float c) {
    return fminf(fminf(a, b), c);   // folds to v_min3_f32
}
template <int CTRL>
__device__ __forceinline__ float dpp_ror_min(float v) {
    int vi = __float_as_int(v);
    int t  = __builtin_amdgcn_update_dpp(vi, vi, CTRL, 0xf, 0xf, true);
    return fminf(v, __int_as_float(t));
}
// min over a 16x16x32 C-fragment's 4 regs x 4 stripes -> scalar
__device__ __forceinline__ float tile_cmin(const f32x4* a) {
    float u0 = fminf(min3f(a[0][0], a[0][1], a[0][2]), a[0][3]);
    float u1 = fminf(min3f(a[1][0], a[1][1], a[1][2]), a[1][3]);
    float u2 = fminf(min3f(a[2][0], a[2][1], a[2][2]), a[2][3]);
    float u3 = fminf(min3f(a[3][0], a[3][1], a[3][2]), a[3][3]);
    return fminf(fminf(u0, u1), fminf(u2, u3));
}

__global__ __launch_bounds__(THREADS, 4)
void chamfer_main(const float* __restrict__ nrf,   // (BP, N, 3) -> y (straight)
                  const float* __restrict__ rp,    // (BP, M, 3) -> x (scrambled)
                  float* __restrict__ out,
                  float inv_bpm, float inv_bpn) {
    __shared__ __align__(16) unsigned char smem[LDS_BYTES];
    float* colW    = (float*)(smem + CW_OFF);
    float* rowsumS = (float*)(smem + RS_OFF);
    float* csumS   = (float*)(smem + CS_OFF);

    const int bp   = blockIdx.x;
    const int tid  = threadIdx.x;
    const int lane = tid & 63;
    const int wave = tid >> 6;
    const int l15  = lane & 15;
    const int g    = lane >> 4;        // k-chunk / row-group id (0..3)
    const unsigned short ONE = 0x3F80;

    const float* yB = nrf + (size_t)bp * NN * 3;
    const float* xB = rp + (size_t)bp * MM * 3;

    // ---- Phase A: stage A panel (x rows, scrambled view) into the B-tile
    // region: thread m builds row m's 4 quads, quad-rotated by (m>>1)&3.
    {
        const int m = tid;
        const int k = 3 * m;
        float v0 = xB[((k    ) & (MM - 1)) * 3 + ((k    ) >> 10)];
        float v1 = xB[((k + 1) & (MM - 1)) * 3 + ((k + 1) >> 10)];
        float v2 = xB[((k + 2) & (MM - 1)) * 3 + ((k + 2) >> 10)];
        float nn = __builtin_fmaf(v0, v0, __builtin_fmaf(v1, v1, v2 * v2));
        S3 a0 = split3(-2.0f * v0), a1 = split3(-2.0f * v1), a2 = split3(-2.0f * v2);
        S3 p = split3(nn);
        uint4 qd[4];
        qd[0] = make_uint4(pk(a0.h0, a0.h0), pk(a0.h1, a0.h1), pk(a0.h0, a0.h2), pk(a1.h0, a1.h0));
        qd[1] = make_uint4(pk(a1.h1, a1.h1), pk(a1.h0, a1.h2), pk(a2.h0, a2.h0), pk(a2.h1, a2.h1));
        qd[2] = make_uint4(pk(a2.h0, a2.h2), pk(p.h0, p.h1), pk(p.h2, ONE), pk(ONE, ONE));
        qd[3] = make_uint4(pk(a0.h1, a0.h2), pk(a1.h1, a1.h2), pk(a2.h1, a2.h2), 0u);
        unsigned char* rowBase = smem + BT_OFF + m * 64;
        const int rot = (m >> 1) & 3;
        #pragma unroll
        for (int qq = 0; qq < 4; ++qq)
            *(uint4*)(rowBase + (((qq + rot) & 3) * 16)) = qd[qq];
    }
    __syncthreads();

    // ---- Phase B: lanes read their 4 A-fragments (1KB contiguous per stripe,
    // conflict-free; values bit-identical to R14's VALU-built fragments).
    bf16x8 af[4];
    {
        const unsigned rdoff = (unsigned)(l15 * 64 + (((g + (l15 >> 1)) & 3) * 16));
        #pragma unroll
        for (int s = 0; s < 4; ++s)
            af[s] = *(const bf16x8*)(smem + BT_OFF + (wave * 64 + s * 16) * 64 + rdoff);
    }
    __syncthreads();

    // ---- Phase C: stage B panel (y cols) over the same region, quad-rotated.
    {
        const int c = tid;
        float v0 = yB[c * 3 + 0], v1 = yB[c * 3 + 1], v2 = yB[c * 3 + 2];
        float nn = __builtin_fmaf(v0, v0, __builtin_fmaf(v1, v1, v2 * v2));
        S3 b0 = split3(v0), b1 = split3(v1), b2 = split3(v2), q = split3(nn);
        uint4 qd[4];
        qd[0] = make_uint4(pk(b0.h0, b0.h1), pk(b0.h0, b0.h1), pk(b0.h2, b0.h0), pk(b1.h0, b1.h1));
        qd[1] = make_uint4(pk(b1.h0, b1.h1), pk(b1.h2, b1.h0), pk(b2.h0, b2.h1), pk(b2.h0, b2.h1));
        qd[2] = make_uint4(pk(b2.h2, b2.h0), pk(ONE, ONE), pk(ONE, q.h0), pk(q.h1, q.h2));
        qd[3] = make_uint4(pk(b0.h2, b0.h1), pk(b1.h2, b1.h1), pk(b2.h2, b2.h1), 0u);
        unsigned char* colBase = smem + BT_OFF + (c >> 4) * 1024 + (c & 15) * 64;
        const int rot = (c >> 1) & 3;
        #pragma unroll
        for (int qq = 0; qq < 4; ++qq)
            *(uint4*)(colBase + (((qq + rot) & 3) * 16)) = qd[qq];
    }
    __syncthreads();

    // ---- main loop: 2-tile pipeline, bounded unroll; row-min AND col-min.
    const unsigned char* BtBase = smem + BT_OFF + (unsigned)(l15 * 64)
                                + (unsigned)((((g + (l15 >> 1)) & 3) * 16));
    const f32x4 Z = {0.0f, 0.0f, 0.0f, 0.0f};
    const int xaddr32 = (lane ^ 32) << 2;
    float* colWrow = colW + wave * 1024 + l15;

    float rmin[4][4];
    #pragma unroll
    for (int s = 0; s < 4; ++s)
        #pragma unroll
        for (int j = 0; j < 4; ++j) rmin[s][j] = FINF;

    bf16x8 c0 = *(const bf16x8*)(BtBase);
    bf16x8 c1 = *(const bf16x8*)(BtBase + 1024);
    #pragma unroll 2
    for (int t = 0; t < 64; t += 2) {
        // prefetch tiles t+2, t+3 (last iter reads the 2KB pad: unused)
        bf16x8 n0 = *(const bf16x8*)(BtBase + (t + 2) * 1024);
        bf16x8 n1 = *(const bf16x8*)(BtBase + (t + 3) * 1024);

        f32x4 aA[4], aB[4];
        #pragma unroll
        for (int s = 0; s < 4; ++s) {
            aA[s] = __builtin_amdgcn_mfma_f32_16x16x32_bf16(af[s], c0, Z, 0, 0, 0);
            aB[s] = __builtin_amdgcn_mfma_f32_16x16x32_bf16(af[s], c1, Z, 0, 0, 0);
        }
        #pragma unroll
        for (int s = 0; s < 4; ++s)
            #pragma unroll
            for (int j = 0; j < 4; ++j)
                rmin[s][j] = min3f(rmin[s][j], aA[s][j], aB[s][j]);

        // per-tile col-min: lane tree -> merge g^1 (swizzle xor16) ->
        // merge g^2 (bpermute xor32) -> lanes 0..15 store.
        {
            float cm = tile_cmin(aA);
            int sw = __builtin_amdgcn_ds_swizzle(__float_as_int(cm), 0x401F);
            cm = fminf(cm, __int_as_float(sw));
            int pz = __builtin_amdgcn_ds_bpermute(xaddr32, __float_as_int(cm));
            cm = fminf(cm, __int_as_float(pz));
            if (g == 0) colWrow[t * 16] = cm;
        }
        {
            float cm = tile_cmin(aB);
            int sw = __builtin_amdgcn_ds_swizzle(__float_as_int(cm), 0x401F);
            cm = fminf(cm, __int_as_float(sw));
            int pz = __builtin_amdgcn_ds_bpermute(xaddr32, __float_as_int(cm));
            cm = fminf(cm, __int_as_float(pz));
            if (g == 0) colWrow[(t + 1) * 16] = cm;
        }
        c0 = n0; c1 = n1;
    }

    // ---- row-min: min over cols = over the 16 lanes of each row group.
    float rowsum = 0.0f;
    #pragma unroll
    for (int s = 0; s < 4; ++s) {
        #pragma unroll
        for (int j = 0; j < 4; ++j) {
            float v = rmin[s][j];
            v = dpp_ror_min<0x121>(v);
            v = dpp_ror_min<0x122>(v);
            v = dpp_ror_min<0x124>(v);
            v = dpp_ror_min<0x128>(v);   // min over the 16 lanes of group g
            rowsum += v;                 // row = s*16 + g*4 + j, all distinct
        }
    }
    // sum across the 4 groups: xor16 (swizzle) + xor32 (bpermute)
    rowsum += __int_as_float(__builtin_amdgcn_ds_swizzle(__float_as_int(rowsum), 0x401F));
    rowsum += __int_as_float(__builtin_amdgcn_ds_bpermute(xaddr32, __float_as_int(rowsum)));
    if (lane == 0) rowsumS[wave] = rowsum;
    __syncthreads();

    // ---- cross-wave col-min merge + column sum (1 col per thread)
    {
        const int c = tid;
        float v = colW[c];
        #pragma unroll
        for (int w = 1; w < NWAVES; ++w) v = fminf(v, colW[w * 1024 + c]);
        float csum = v;
        #pragma unroll
        for (int off = 32; off > 0; off >>= 1) csum += __shfl_xor(csum, off, 64);
        if (lane == 0) csumS[wave] = csum;
    }
    __syncthreads();

    if (tid == 0) {
        float rs = 0.0f, cs = 0.0f;
        #pragma unroll
        for (int w = 0; w < NWAVES; ++w) { rs += rowsumS[w]; cs += csumS[w]; }
        atomicAdd(out, rs * inv_bpm + cs * inv_bpn);
    }
}

extern "C" void kernel_launch(void* const* d_in, const int* in_sizes, int n_in,
                              void* d_out, int out_size, void* d_ws, size_t ws_size,
                              hipStream_t stream) {
    const float* nrf = (const float*)d_in[0];  // (B,P,N,3)
    const float* rp  = (const float*)d_in[1];  // (B,P,M,3)
    float* out = (float*)d_out;

    const int BP = in_sizes[1] / (MM * 3);     // 256
    const float inv_bpm = 1.0f / (float)(BP * MM);
    const float inv_bpn = 1.0f / (float)(BP * NN);

    (void)hipMemsetAsync(out, 0, sizeof(float), stream);
    chamfer_main<<<BP, THREADS, 0, stream>>>(nrf, rp, out, inv_bpm, inv_bpn);
}